// Round 7
// baseline (868.844 us; speedup 1.0000x reference)
//
#include <hip/hip_runtime.h>
#include <hip/hip_bf16.h>
#include <hip/hip_cooperative_groups.h>
#include <stdint.h>
#include <stddef.h>

namespace cg = cooperative_groups;

// DecoderStepLayer R6: cooperative mega-kernel with grid-stride phases and a
// guaranteed fallback: if hipLaunchCooperativeKernel returns an error (R5's
// silent failure), launch the same phases as 12 ordinary kernels. Both paths
// run IDENTICAL phase device-functions -> bit-identical outputs.

#define DEV __device__ __forceinline__

typedef __attribute__((ext_vector_type(8))) short bf16x8;
typedef __attribute__((ext_vector_type(4))) float f32x4;

DEV unsigned short f2b(float f){
  union { __hip_bfloat16 h; unsigned short u; } cv;
  cv.h = __float2bfloat16(f);
  return cv.u;
}
DEV float b2f(unsigned short u){
  union { unsigned int i; float f; } cv;
  cv.i = ((unsigned int)u) << 16;
  return cv.f;
}
DEV f32x4 mfma16(bf16x8 a, bf16x8 b, f32x4 c){
  return __builtin_amdgcn_mfma_f32_16x16x32_bf16(a, b, c, 0, 0, 0);
}

struct Params {
  const float *dec, *hist, *enc;
  const float *wq_s, *wk_s, *wv_s, *wo_s, *bo_s, *ln1_g, *ln1_b;
  const float *wq_c, *wk_c, *wv_c, *wo_c, *bo_c, *ln2_g, *ln2_b;
  const float *w1, *b1, *w2, *b2, *ln3_g, *ln3_b;
  float *out, *slf, *enco;
  float *scr, *msum, *x1, *x2, *gpart, *fpart, *g2part;
  unsigned short *partb, *qpb, *x2b, *h1b;
};

// ---------------------------------------------------------------------------
// qp2 phase (unit u in [0,256)): fused dec->Q->qp projections.
DEV void ph_qp2(unsigned char* sm, int u, const float* __restrict__ src,
    const float* __restrict__ wq, const float* __restrict__ wk,
    unsigned short* __restrict__ qpb){
  int b = u >> 4, h = u & 15;
  int t = threadIdx.x;
  float* red = (float*)sm;        // 256
  float* Qs  = red + 256;         // 64
  {
    int k = t & 63, q = t >> 6;
    const float* s = src + (size_t)b*1024 + q*256;
    const float* w = wq + (size_t)h*65536 + (size_t)(q*256)*64 + k;
    float a0=0.f,a1=0.f,a2=0.f,a3=0.f;
    for(int d=0; d<256; d+=4){
      a0 += s[d]   * w[(size_t)d*64];
      a1 += s[d+1] * w[(size_t)(d+1)*64];
      a2 += s[d+2] * w[(size_t)(d+2)*64];
      a3 += s[d+3] * w[(size_t)(d+3)*64];
    }
    red[t] = a0+a1+a2+a3;
    __syncthreads();
    if(t < 64) Qs[t] = (red[t]+red[t+64]+red[t+128]+red[t+192])*0.125f;
    __syncthreads();
  }
  for(int i=0;i<4;++i){
    int d = t + i*256;
    const float* w = wk + ((size_t)h*1024 + d)*64;
    float acc = 0.f;
    #pragma unroll
    for(int k4=0;k4<16;++k4){
      float4 wv4 = *(const float4*)(w + k4*4);
      acc += wv4.x*Qs[k4*4] + wv4.y*Qs[k4*4+1] + wv4.z*Qs[k4*4+2] + wv4.w*Qs[k4*4+3];
    }
    qpb[(size_t)u*1024 + d] = f2b(acc);
  }
  __syncthreads();
}

// ---------------------------------------------------------------------------
// attn phase (unit u in [0,512)): ns = u&31, b = u>>5. 64 rows, 4 chunks of 16.
DEV void ph_attn(unsigned char* sm, int u, const float* __restrict__ kvsrc,
    const float* __restrict__ decrow, const unsigned short* __restrict__ qpb,
    float* __restrict__ scr, unsigned short* __restrict__ partb,
    float* __restrict__ msum, int lsrc){
  int ns = u & 31, b = u >> 5;
  int t = threadIdx.x, lane = t & 63, w = t >> 6;
  int r = lane & 15, hi = lane >> 4;
  int slice0 = ns*64;

  unsigned short* lt    = (unsigned short*)sm;            // 48 KB [d 1024][l 24]
  float*          red   = (float*)(sm + 49152);           // 4 KB
  unsigned short* p_lds = (unsigned short*)(sm + 53248);  // 1.25 KB [16][40]
  float*          f_lds = (float*)(sm + 54528);           // 64 B

  float4 ld[16];
  auto ISSUE = [&](int c){
    int row = slice0 + c*16 + r;
    const float* rp = (row < lsrc) ? kvsrc + ((size_t)b*lsrc + row)*1024
                                   : decrow + (size_t)b*1024;
    rp += w*256 + hi*8;
    #pragma unroll
    for(int kk=0; kk<8; ++kk){
      ld[kk*2+0] = *(const float4*)(rp + kk*32);
      ld[kk*2+1] = *(const float4*)(rp + kk*32 + 4);
    }
  };

  ISSUE(0);
  for(int i=t; i<16*40; i+=256) p_lds[i] = 0;

  bf16x8 qf[8];
  {
    const unsigned short* qp = qpb + ((size_t)b*16 + r)*1024 + w*256 + hi*8;
    #pragma unroll
    for(int kk=0;kk<8;++kk) qf[kk] = *(const bf16x8*)(qp + kk*32);
  }

  f32x4 acc[16];
  #pragma unroll
  for(int i=0;i<16;++i) acc[i] = (f32x4){0.f,0.f,0.f,0.f};
  float m_run = -1e30f, s_run = 0.f;

  __syncthreads();                         // p_lds zeros visible
  for(int c=0; c<4; ++c){
    f32x4 s_acc = {0.f,0.f,0.f,0.f};
    int colw = r ^ ((hi & 1) << 3);
    #pragma unroll
    for(int kk=0; kk<8; ++kk){
      float4 a0 = ld[kk*2], a1 = ld[kk*2+1];
      bf16x8 v;
      v[0]=(short)f2b(a0.x); v[1]=(short)f2b(a0.y);
      v[2]=(short)f2b(a0.z); v[3]=(short)f2b(a0.w);
      v[4]=(short)f2b(a1.x); v[5]=(short)f2b(a1.y);
      v[6]=(short)f2b(a1.z); v[7]=(short)f2b(a1.w);
      unsigned short* pt = &lt[(w*256 + hi*8 + kk*32)*24 + colw];
      #pragma unroll
      for(int j=0;j<8;++j) pt[j*24] = (unsigned short)v[j];
      s_acc = mfma16(v, qf[kk], s_acc);
    }
    if(c < 3) ISSUE(c+1);
    *(f32x4*)&red[t*4] = s_acc;
    __syncthreads();                       // (A) red + lt visible

    f32x4 ss = *(const f32x4*)&red[(0*64+lane)*4];
    ss += *(const f32x4*)&red[(1*64+lane)*4];
    ss += *(const f32x4*)&red[(2*64+lane)*4];
    ss += *(const f32x4*)&red[(3*64+lane)*4];
    float sf[4] = {ss[0], ss[1], ss[2], ss[3]};
    float mc = fmaxf(fmaxf(sf[0],sf[1]), fmaxf(sf[2],sf[3]));
    mc = fmaxf(mc, __shfl_xor(mc, 16));
    mc = fmaxf(mc, __shfl_xor(mc, 32));
    float nm = fmaxf(m_run, mc);
    float fch = __expf(m_run - nm);
    float pvv[4]; float ps = 0.f;
    #pragma unroll
    for(int i=0;i<4;++i){ pvv[i] = __expf(sf[i]-nm); ps += pvv[i]; }
    ps += __shfl_xor(ps, 16);
    ps += __shfl_xor(ps, 32);
    s_run = s_run*fch + ps;
    m_run = nm;
    if(w == 0){
      #pragma unroll
      for(int i=0;i<4;++i) p_lds[r*40 + hi*4 + i] = f2b(pvv[i]);
      if(hi == 0) f_lds[r] = fch;
      float* sp = scr + ((size_t)b*16 + r)*2048 + slice0 + c*16 + hi*4;
      *(float4*)sp = (float4){sf[0], sf[1], sf[2], sf[3]};
    }
    __syncthreads();                       // (B) p_lds, f_lds ready

    f32x4 fv = *(const f32x4*)&f_lds[hi*4];
    bf16x8 pa = *(const bf16x8*)&p_lds[r*40 + hi*8];
    #pragma unroll
    for(int dc=0; dc<16; ++dc){
      acc[dc] *= fv;
      int d = w*256 + dc*16 + r;
      int col0 = (((hi & 1) ^ ((r >> 3) & 1)) << 3);
      bf16x8 bv = *(const bf16x8*)&lt[d*24 + col0];
      acc[dc] = mfma16(pa, bv, acc[dc]);
    }
    __syncthreads();                       // (C) PV reads done before next deposit
  }
  // epilogue: bf16 partial ctx staged via LDS for coalesced 32 KB store
  unsigned short* pl = lt;                 // reuse: [h 16][d 1024]
  #pragma unroll
  for(int dc=0; dc<16; ++dc)
    #pragma unroll
    for(int i=0;i<4;++i)
      pl[(hi*4+i)*1024 + w*256 + dc*16 + r] = f2b(acc[dc][i]);
  __syncthreads();
  {
    const uint4* s4 = (const uint4*)pl;
    uint4* d4 = (uint4*)(partb + (((size_t)b*32 + ns)*16)*1024);
    #pragma unroll
    for(int j=0;j<8;++j) d4[t + j*256] = s4[t + j*256];
  }
  if(w==0 && hi==0){
    msum[(((size_t)b*32 + ns)*16 + r)*2 + 0] = m_run;
    msum[(((size_t)b*32 + ns)*16 + r)*2 + 1] = s_run;
  }
  __syncthreads();
}

// ---------------------------------------------------------------------------
// fin phase (unit u in [0,256)): combine slices + probs + V-proj + wo-partial.
DEV void ph_fin(unsigned char* sm, int u, const unsigned short* __restrict__ partb,
    const float* __restrict__ msum, const float* __restrict__ scr,
    const float* __restrict__ wv, const float* __restrict__ wo,
    float* __restrict__ attn_out, float* __restrict__ gpart){
  int b = u >> 4, h = u & 15;
  int t = threadIdx.x;
  float* marr = (float*)sm;        // 32
  float* earr = marr + 32;         // 32
  float* ctxs = earr + 32;         // 1024
  float* red2 = ctxs + 1024;       // 256
  float* obh  = red2 + 256;        // 64
  if(t < 32){
    marr[t] = msum[(((size_t)b*32 + t)*16 + h)*2 + 0];
    earr[t] = msum[(((size_t)b*32 + t)*16 + h)*2 + 1];   // temp: slice sums
  }
  __syncthreads();
  float M = -1e30f;
  for(int i=0;i<32;++i) M = fmaxf(M, marr[i]);
  float SUM = 0.f;
  for(int i=0;i<32;++i) SUM += __expf(marr[i]-M)*earr[i];
  float inv = 1.f/SUM;
  __syncthreads();
  if(t < 32) earr[t] = __expf(marr[t]-M)*inv;            // normalized weights
  __syncthreads();
  {
    const unsigned short* pb0 = partb + ((size_t)b*32*16 + h)*1024 + t*4;
    float ax=0.f, ay=0.f, az=0.f, aw=0.f;
    for(int nsq=0; nsq<32; ++nsq){
      ushort4 uu = *(const ushort4*)(pb0 + (size_t)nsq*16384);
      float e = earr[nsq];
      ax += e*b2f(uu.x); ay += e*b2f(uu.y); az += e*b2f(uu.z); aw += e*b2f(uu.w);
    }
    *(float4*)&ctxs[t*4] = (float4){ax,ay,az,aw};
  }
  const float* sp = scr + ((size_t)b*16 + h)*2048;
  float* po = attn_out + ((size_t)b*16 + h)*2048;
  #pragma unroll
  for(int i=0;i<8;++i){ int l = t + i*256; po[l] = __expf(sp[l]-M)*inv; }
  __syncthreads();
  // head V-proj: obh[v] = sum_d ctx[d]*wv[h,d,v]
  int v = t & 63, q = t >> 6;
  const float* wp = wv + ((size_t)h*1024 + q*256)*64 + v;
  float a0=0.f,a1=0.f,a2=0.f,a3=0.f;
  for(int dd=0; dd<256; dd+=4){
    a0 += ctxs[q*256+dd]   * wp[(size_t)dd*64];
    a1 += ctxs[q*256+dd+1] * wp[(size_t)(dd+1)*64];
    a2 += ctxs[q*256+dd+2] * wp[(size_t)(dd+2)*64];
    a3 += ctxs[q*256+dd+3] * wp[(size_t)(dd+3)*64];
  }
  red2[t] = a0+a1+a2+a3;
  __syncthreads();
  if(t < 64) obh[t] = red2[t]+red2[t+64]+red2[t+128]+red2[t+192];
  __syncthreads();
  // fused wo-partial: gpart[(h*16+b)*1024 + n] = sum_v obh[v]*wo[h*64+v][n]
  float accn[4] = {0.f,0.f,0.f,0.f};
  const float* wrow = wo + (size_t)h*64*1024;
  for(int vv=0; vv<64; ++vv){
    float s = obh[vv];
    const float* wr = wrow + (size_t)vv*1024;
    #pragma unroll
    for(int i=0;i<4;++i) accn[i] += s * wr[t + i*256];
  }
  #pragma unroll
  for(int i=0;i<4;++i) gpart[((size_t)h*16 + b)*1024 + t + i*256] = accn[i];
  __syncthreads();
}

// ---------------------------------------------------------------------------
// LN phase (unit b in [0,16)).
DEV void ph_ln(unsigned char* sm, int b, const float* __restrict__ parts, int KS,
    const float* __restrict__ bias, const float* __restrict__ resid,
    const float* __restrict__ g, const float* __restrict__ bb,
    float* __restrict__ xout, unsigned short* __restrict__ xb16){
  int t = threadIdx.x;
  float* red = (float*)sm;
  const float4* bias4  = (const float4*)bias;
  const float4* resid4 = (const float4*)resid + (size_t)b*256;
  const float4* parts4 = (const float4*)parts;
  float4 s = bias4[t];
  { float4 rr = resid4[t]; s.x+=rr.x; s.y+=rr.y; s.z+=rr.z; s.w+=rr.w; }
  #pragma unroll 4
  for(int k=0;k<KS;++k){
    float4 pp = parts4[((size_t)k*16 + b)*256 + t];
    s.x+=pp.x; s.y+=pp.y; s.z+=pp.z; s.w+=pp.w;
  }
  red[t] = s.x+s.y+s.z+s.w; __syncthreads();
  for(int off=128; off>0; off>>=1){ if(t<off) red[t]+=red[t+off]; __syncthreads(); }
  float mean = red[0]*(1.f/1024.f); __syncthreads();
  float dx=s.x-mean, dy=s.y-mean, dz=s.z-mean, dw=s.w-mean;
  red[t] = dx*dx+dy*dy+dz*dz+dw*dw; __syncthreads();
  for(int off=128; off>0; off>>=1){ if(t<off) red[t]+=red[t+off]; __syncthreads(); }
  float rstd = rsqrtf(red[0]*(1.f/1024.f) + 1e-5f);
  float4 g4 = ((const float4*)g)[t], b4 = ((const float4*)bb)[t];
  float4 y;
  y.x = dx*rstd*g4.x + b4.x;
  y.y = dy*rstd*g4.y + b4.y;
  y.z = dz*rstd*g4.z + b4.z;
  y.w = dw*rstd*g4.w + b4.w;
  if(xout) ((float4*)xout)[(size_t)b*256 + t] = y;
  if(xb16){
    ushort4 uu;
    uu.x = f2b(y.x); uu.y = f2b(y.y); uu.z = f2b(y.z); uu.w = f2b(y.w);
    ((ushort4*)xb16)[(size_t)b*256 + t] = uu;
  }
  __syncthreads();
}

// ---------------------------------------------------------------------------
// skinny GEMM phase: part[ks,b,n] = A[16,Kslice] @ W[Kslice,N]
DEV void ph_skg(unsigned char* sm, const float* __restrict__ W,
    const unsigned short* __restrict__ A, float* __restrict__ part,
    int N, int K, int KS, int nt, int ks){
  int Ksl = K / KS, k0b = ks * Ksl, n0 = nt*64;
  int nc = Ksl >> 5;
  unsigned short* lt0 = (unsigned short*)sm;
  unsigned short* lt1 = lt0 + 64*40;
  int t = threadIdx.x, lane = t & 63, w = t >> 6;
  int k_loc = t >> 3, n_off = (t & 7)*8;
  const unsigned short* apb = A + (size_t)(lane & 15)*K + (lane >> 4)*8 + k0b;
  f32x4 acc = {0.f,0.f,0.f,0.f};
  float4 x0, x1;
  auto LD = [&](int c){
    const float* wp = W + (size_t)(k0b + c*32 + k_loc)*N + n0 + n_off;
    x0 = *(const float4*)wp;
    x1 = *(const float4*)(wp + 4);
  };
  auto ST = [&](int buf){
    unsigned short* p = buf ? lt1 : lt0;
    p[(n_off+0)*40 + k_loc] = f2b(x0.x);
    p[(n_off+1)*40 + k_loc] = f2b(x0.y);
    p[(n_off+2)*40 + k_loc] = f2b(x0.z);
    p[(n_off+3)*40 + k_loc] = f2b(x0.w);
    p[(n_off+4)*40 + k_loc] = f2b(x1.x);
    p[(n_off+5)*40 + k_loc] = f2b(x1.y);
    p[(n_off+6)*40 + k_loc] = f2b(x1.z);
    p[(n_off+7)*40 + k_loc] = f2b(x1.w);
  };
  LD(0); ST(0);
  for(int c=0; c<nc; ++c){
    if(c+1 < nc) LD(c+1);
    __syncthreads();
    unsigned short* p = (c&1) ? lt1 : lt0;
    bf16x8 af = *(const bf16x8*)(apb + c*32);
    bf16x8 bv = *(const bf16x8*)&p[(w*16 + (lane & 15))*40 + (lane >> 4)*8];
    acc = mfma16(af, bv, acc);
    if(c+1 < nc) ST((c+1)&1);
  }
  int col = n0 + w*16 + (lane & 15);
  int r0 = (lane >> 4)*4;
  #pragma unroll
  for(int i=0;i<4;++i)
    part[ ((size_t)ks*16 + r0 + i)*(size_t)N + col ] = acc[i];
  __syncthreads();
}

// relu phase (unit u in [0,64)).
DEV void ph_relu(int u, const float* __restrict__ parts, int KS,
    const float* __restrict__ b1, unsigned short* __restrict__ h1){
  int i = u*256 + threadIdx.x;             // float4 units over 16*1024
  int b = i >> 10, f4 = i & 1023;
  float4 s = ((const float4*)b1)[f4];
  #pragma unroll 4
  for(int k=0;k<KS;++k){
    float4 pp = ((const float4*)parts)[((size_t)k*16 + b)*1024 + f4];
    s.x+=pp.x; s.y+=pp.y; s.z+=pp.z; s.w+=pp.w;
  }
  ushort4 uu;
  uu.x = f2b(fmaxf(s.x,0.f)); uu.y = f2b(fmaxf(s.y,0.f));
  uu.z = f2b(fmaxf(s.z,0.f)); uu.w = f2b(fmaxf(s.w,0.f));
  ((ushort4*)h1)[i] = uu;
}

// ---------------------------------------------------------------------------
// Cooperative mega-kernel: grid-stride over phase work units, grid.sync between.
__global__ void __launch_bounds__(256, 2) k_mega(Params p){
  __shared__ __align__(16) unsigned char SM[54784];
  cg::grid_group grid = cg::this_grid();
  int bid = blockIdx.x, G = gridDim.x;

  for(int u=bid; u<256; u+=G) ph_qp2(SM, u, p.dec, p.wq_s, p.wk_s, p.qpb);
  __threadfence(); grid.sync();
  for(int u=bid; u<512; u+=G) ph_attn(SM, u, p.hist, p.dec, p.qpb, p.scr, p.partb, p.msum, 2047);
  __threadfence(); grid.sync();
  for(int u=bid; u<256; u+=G) ph_fin(SM, u, p.partb, p.msum, p.scr, p.wv_s, p.wo_s, p.slf, p.gpart);
  __threadfence(); grid.sync();
  for(int u=bid; u<16; u+=G) ph_ln(SM, u, p.gpart, 16, p.bo_s, p.dec, p.ln1_g, p.ln1_b, p.x1, (unsigned short*)0);
  __threadfence(); grid.sync();

  for(int u=bid; u<256; u+=G) ph_qp2(SM, u, p.x1, p.wq_c, p.wk_c, p.qpb);
  __threadfence(); grid.sync();
  for(int u=bid; u<512; u+=G) ph_attn(SM, u, p.enc, p.dec, p.qpb, p.scr, p.partb, p.msum, 2048);
  __threadfence(); grid.sync();
  for(int u=bid; u<256; u+=G) ph_fin(SM, u, p.partb, p.msum, p.scr, p.wv_c, p.wo_c, p.enco, p.gpart);
  __threadfence(); grid.sync();
  for(int u=bid; u<16; u+=G) ph_ln(SM, u, p.gpart, 16, p.bo_c, p.x1, p.ln2_g, p.ln2_b, p.x2, p.x2b);
  __threadfence(); grid.sync();

  for(int u=bid; u<512; u+=G) ph_skg(SM, p.w1, p.x2b, p.fpart, 4096, 1024, 8, u & 63, u >> 6);
  __threadfence(); grid.sync();
  for(int u=bid; u<64; u+=G) ph_relu(u, p.fpart, 8, p.b1, p.h1b);
  __threadfence(); grid.sync();
  for(int u=bid; u<512; u+=G) ph_skg(SM, p.w2, p.h1b, p.g2part, 1024, 4096, 32, u & 15, u >> 4);
  __threadfence(); grid.sync();
  for(int u=bid; u<16; u+=G) ph_ln(SM, u, p.g2part, 32, p.b2, p.x2, p.ln3_g, p.ln3_b, p.out, (unsigned short*)0);
}

// ---------------------------------------------------------------------------
// Fallback wrappers (identical phase functions, ordinary launches).
__global__ __launch_bounds__(256) void g_qp2(const float* src, const float* wq,
    const float* wk, unsigned short* qpb){
  __shared__ __align__(16) unsigned char SM[1280];
  ph_qp2(SM, blockIdx.x, src, wq, wk, qpb);
}
__global__ __launch_bounds__(256) void g_attn(const float* kvsrc, const float* decrow,
    const unsigned short* qpb, float* scr, unsigned short* partb, float* msum, int lsrc){
  __shared__ __align__(16) unsigned char SM[54784];
  ph_attn(SM, blockIdx.x, kvsrc, decrow, qpb, scr, partb, msum, lsrc);
}
__global__ __launch_bounds__(256) void g_fin(const unsigned short* partb,
    const float* msum, const float* scr, const float* wv, const float* wo,
    float* attn_out, float* gpart){
  __shared__ __align__(16) unsigned char SM[5632];
  ph_fin(SM, blockIdx.x, partb, msum, scr, wv, wo, attn_out, gpart);
}
__global__ __launch_bounds__(256) void g_ln(const float* parts, int KS,
    const float* bias, const float* resid, const float* g, const float* bb,
    float* xout, unsigned short* xb16){
  __shared__ __align__(16) unsigned char SM[1024];
  ph_ln(SM, blockIdx.x, parts, KS, bias, resid, g, bb, xout, xb16);
}
__global__ __launch_bounds__(256) void g_skg(const float* W, const unsigned short* A,
    float* part, int N, int K, int KS){
  __shared__ __align__(16) unsigned char SM[10240];
  ph_skg(SM, W, A, part, N, K, KS, blockIdx.x, blockIdx.y);
}
__global__ __launch_bounds__(256) void g_relu(const float* parts, int KS,
    const float* b1, unsigned short* h1){
  ph_relu(blockIdx.x, parts, KS, b1, h1);
}

// ---------------------------------------------------------------------------
extern "C" void kernel_launch(void* const* d_in, const int* in_sizes, int n_in,
                              void* d_out, int out_size, void* d_ws, size_t ws_size,
                              hipStream_t stream){
  Params p;
  p.dec    = (const float*)d_in[0];
  p.hist   = (const float*)d_in[1];
  p.enc    = (const float*)d_in[2];
  p.wq_s   = (const float*)d_in[3];
  p.wk_s   = (const float*)d_in[4];
  p.wv_s   = (const float*)d_in[5];
  p.wo_s   = (const float*)d_in[6];
  p.bo_s   = (const float*)d_in[7];
  p.ln1_g  = (const float*)d_in[8];
  p.ln1_b  = (const float*)d_in[9];
  p.wq_c   = (const float*)d_in[10];
  p.wk_c   = (const float*)d_in[11];
  p.wv_c   = (const float*)d_in[12];
  p.wo_c   = (const float*)d_in[13];
  p.bo_c   = (const float*)d_in[14];
  p.ln2_g  = (const float*)d_in[15];
  p.ln2_b  = (const float*)d_in[16];
  p.w1     = (const float*)d_in[17];
  p.b1     = (const float*)d_in[18];
  p.w2     = (const float*)d_in[19];
  p.b2     = (const float*)d_in[20];
  p.ln3_g  = (const float*)d_in[21];
  p.ln3_b  = (const float*)d_in[22];

  float* out = (float*)d_out;
  p.out  = out;                    // [16][1024]
  p.slf  = out + 16384;            // [16][16][2048]
  p.enco = out + 16384 + 524288;   // [16][16][2048]

  char* w = (char*)d_ws;
  p.scr    = (float*)(w + 0x0000000);            // 2 MB  [16][16][2048] fp32
  p.partb  = (unsigned short*)(w + 0x0200000);   // 16 MB [16][32][16][1024] bf16
  p.msum   = (float*)(w + 0x1200000);            // 64K
  p.qpb    = (unsigned short*)(w + 0x1210000);   // 512K
  p.x1     = (float*)(w + 0x1290000);            // 64K
  p.x2     = (float*)(w + 0x12A0000);            // 64K
  p.x2b    = (unsigned short*)(w + 0x12B0000);   // 32K
  p.h1b    = (unsigned short*)(w + 0x12C0000);   // 128K
  p.gpart  = (float*)(w + 0x1300000);            // 1 MB  [16][16][1024]
  p.fpart  = (float*)(w + 0x1400000);            // 2 MB  [8][16][4096]
  p.g2part = (float*)(w + 0x1600000);            // 2 MB  [32][16][1024]

  // Try cooperative mega-kernel; fall back to 12 ordinary launches on failure.
  bool coop_done = false;
  int nb = 0;
  hipError_t qerr = hipOccupancyMaxActiveBlocksPerMultiprocessor(
      &nb, (const void*)k_mega, 256, 0);
  if(qerr == hipSuccess && nb >= 1){
    int G = (nb >= 2) ? 512 : 256;
    void* args[] = { &p };
    hipError_t lerr = hipLaunchCooperativeKernel((const void*)k_mega, dim3(G),
                                                 dim3(256), args, 0, stream);
    coop_done = (lerr == hipSuccess);
  }
  if(!coop_done){
    g_qp2 <<<256, 256, 0, stream>>>(p.dec, p.wq_s, p.wk_s, p.qpb);
    g_attn<<<512, 256, 0, stream>>>(p.hist, p.dec, p.qpb, p.scr, p.partb, p.msum, 2047);
    g_fin <<<256, 256, 0, stream>>>(p.partb, p.msum, p.scr, p.wv_s, p.wo_s, p.slf, p.gpart);
    g_ln  <<<16,  256, 0, stream>>>(p.gpart, 16, p.bo_s, p.dec, p.ln1_g, p.ln1_b, p.x1, (unsigned short*)0);
    g_qp2 <<<256, 256, 0, stream>>>(p.x1, p.wq_c, p.wk_c, p.qpb);
    g_attn<<<512, 256, 0, stream>>>(p.enc, p.dec, p.qpb, p.scr, p.partb, p.msum, 2048);
    g_fin <<<256, 256, 0, stream>>>(p.partb, p.msum, p.scr, p.wv_c, p.wo_c, p.enco, p.gpart);
    g_ln  <<<16,  256, 0, stream>>>(p.gpart, 16, p.bo_c, p.x1, p.ln2_g, p.ln2_b, p.x2, p.x2b);
    g_skg <<<dim3(64,8),  256, 0, stream>>>(p.w1, p.x2b, p.fpart, 4096, 1024, 8);
    g_relu<<<64,  256, 0, stream>>>(p.fpart, 8, p.b1, p.h1b);
    g_skg <<<dim3(16,32), 256, 0, stream>>>(p.w2, p.h1b, p.g2part, 1024, 4096, 32);
    g_ln  <<<16,  256, 0, stream>>>(p.g2part, 32, p.b2, p.x2, p.ln3_g, p.ln3_b, p.out, (unsigned short*)0);
  }
}

// Round 8
// 194.711 us; speedup vs baseline: 4.4622x; 4.4622x over previous
//
#include <hip/hip_runtime.h>
#include <hip/hip_bf16.h>
#include <stdint.h>
#include <stddef.h>

// DecoderStepLayer R7: 12 ordinary kernels (coop mega-kernel abandoned:
// grid.sync ~65us each on MI355X -> 868us total, VALUBusy 1%).
// vs R5: bf16 ctx partials, wo-GEMM fused into fin, attn occupancy raised
// (32-row blocks, NS=64, grid 1024; LDS 46.4KB via lt pitch 20 -> 3 blocks/CU).

#define DEV __device__ __forceinline__

typedef __attribute__((ext_vector_type(8))) short bf16x8;
typedef __attribute__((ext_vector_type(4))) short bf16x4;
typedef __attribute__((ext_vector_type(4))) float f32x4;

DEV unsigned short f2b(float f){
  union { __hip_bfloat16 h; unsigned short u; } cv;
  cv.h = __float2bfloat16(f);
  return cv.u;
}
DEV float b2f(unsigned short u){
  union { unsigned int i; float f; } cv;
  cv.i = ((unsigned int)u) << 16;
  return cv.f;
}
DEV f32x4 mfma16(bf16x8 a, bf16x8 b, f32x4 c){
  return __builtin_amdgcn_mfma_f32_16x16x32_bf16(a, b, c, 0, 0, 0);
}

// ---------------------------------------------------------------------------
// qp2: qpb[b,h,d] = bf16( sum_k wk[h,d,k] * (0.125*sum_d' src[b,d']*wq[h,d',k]) )
__global__ __launch_bounds__(256) void g_qp2(const float* __restrict__ src,
    const float* __restrict__ wq, const float* __restrict__ wk,
    unsigned short* __restrict__ qpb){
  int u = blockIdx.x, b = u >> 4, h = u & 15;
  int t = threadIdx.x;
  __shared__ float red[256];
  __shared__ float Qs[64];
  {
    int k = t & 63, q = t >> 6;
    const float* s = src + (size_t)b*1024 + q*256;
    const float* w = wq + (size_t)h*65536 + (size_t)(q*256)*64 + k;
    float a0=0.f,a1=0.f,a2=0.f,a3=0.f;
    for(int d=0; d<256; d+=4){
      a0 += s[d]   * w[(size_t)d*64];
      a1 += s[d+1] * w[(size_t)(d+1)*64];
      a2 += s[d+2] * w[(size_t)(d+2)*64];
      a3 += s[d+3] * w[(size_t)(d+3)*64];
    }
    red[t] = a0+a1+a2+a3;
    __syncthreads();
    if(t < 64) Qs[t] = (red[t]+red[t+64]+red[t+128]+red[t+192])*0.125f;
    __syncthreads();
  }
  for(int i=0;i<4;++i){
    int d = t + i*256;
    const float* w = wk + ((size_t)h*1024 + d)*64;
    float acc = 0.f;
    #pragma unroll
    for(int k4=0;k4<16;++k4){
      float4 wv4 = *(const float4*)(w + k4*4);
      acc += wv4.x*Qs[k4*4] + wv4.y*Qs[k4*4+1] + wv4.z*Qs[k4*4+2] + wv4.w*Qs[k4*4+3];
    }
    qpb[(size_t)u*1024 + d] = f2b(acc);
  }
}

// ---------------------------------------------------------------------------
// attn: grid 1024 = (ns 64, b 16). Block = 32 rows, 2 chunks of 16.
// lt transposed [d 1024][l pitch 20], XOR low-swizzle; PV reads 2x bf16x4 (b64).
__global__ __launch_bounds__(256) void g_attn(const float* __restrict__ kvsrc,
    const float* __restrict__ decrow, const unsigned short* __restrict__ qpb,
    float* __restrict__ scr, unsigned short* __restrict__ partb,
    float* __restrict__ msum, int lsrc){
  int u = blockIdx.x, ns = u & 63, b = u >> 6;
  int t = threadIdx.x, lane = t & 63, w = t >> 6;
  int r = lane & 15, hi = lane >> 4;
  int slice0 = ns*32;

  __shared__ unsigned short lt[1024*20];   // 40 KB transposed KV tile
  __shared__ float red[1024];              // 4 KB cross-wave score reduce
  __shared__ unsigned short p_lds[16*40];  // [h][l 0..31], cols 16..31 stay 0
  __shared__ float f_lds[16];              // per-h rescale factor

  float4 ld[16];
  auto ISSUE = [&](int c){
    int row = slice0 + c*16 + r;
    const float* rp = (row < lsrc) ? kvsrc + ((size_t)b*lsrc + row)*1024
                                   : decrow + (size_t)b*1024;
    rp += w*256 + hi*8;
    #pragma unroll
    for(int kk=0; kk<8; ++kk){
      ld[kk*2+0] = *(const float4*)(rp + kk*32);
      ld[kk*2+1] = *(const float4*)(rp + kk*32 + 4);
    }
  };

  ISSUE(0);
  for(int i=t; i<16*40; i+=256) p_lds[i] = 0;

  bf16x8 qf[8];
  {
    const unsigned short* qp = qpb + ((size_t)b*16 + r)*1024 + w*256 + hi*8;
    #pragma unroll
    for(int kk=0;kk<8;++kk) qf[kk] = *(const bf16x8*)(qp + kk*32);
  }

  f32x4 acc[16];
  #pragma unroll
  for(int i=0;i<16;++i) acc[i] = (f32x4){0.f,0.f,0.f,0.f};
  float m_run = -1e30f, s_run = 0.f;

  __syncthreads();                         // p_lds zeros visible
  for(int c=0; c<2; ++c){
    // ---- scores + transposed LDS deposit ----
    f32x4 s_acc = {0.f,0.f,0.f,0.f};
    int colw = r ^ ((hi & 1) << 3);
    #pragma unroll
    for(int kk=0; kk<8; ++kk){
      float4 a0 = ld[kk*2], a1 = ld[kk*2+1];
      bf16x8 v;
      v[0]=(short)f2b(a0.x); v[1]=(short)f2b(a0.y);
      v[2]=(short)f2b(a0.z); v[3]=(short)f2b(a0.w);
      v[4]=(short)f2b(a1.x); v[5]=(short)f2b(a1.y);
      v[6]=(short)f2b(a1.z); v[7]=(short)f2b(a1.w);
      unsigned short* pt = &lt[(w*256 + hi*8 + kk*32)*20 + colw];
      #pragma unroll
      for(int j=0;j<8;++j) pt[j*20] = (unsigned short)v[j];
      s_acc = mfma16(v, qf[kk], s_acc);
    }
    if(c < 1) ISSUE(c+1);                  // next chunk's loads fly through SM+PV
    *(f32x4*)&red[t*4] = s_acc;
    __syncthreads();                       // (A) red + lt visible

    // ---- all-wave redundant online softmax (h = r, l = hi*4+i) ----
    f32x4 ss = *(const f32x4*)&red[(0*64+lane)*4];
    ss += *(const f32x4*)&red[(1*64+lane)*4];
    ss += *(const f32x4*)&red[(2*64+lane)*4];
    ss += *(const f32x4*)&red[(3*64+lane)*4];
    float sf[4] = {ss[0], ss[1], ss[2], ss[3]};
    float mc = fmaxf(fmaxf(sf[0],sf[1]), fmaxf(sf[2],sf[3]));
    mc = fmaxf(mc, __shfl_xor(mc, 16));
    mc = fmaxf(mc, __shfl_xor(mc, 32));
    float nm = fmaxf(m_run, mc);
    float fch = __expf(m_run - nm);
    float pvv[4]; float ps = 0.f;
    #pragma unroll
    for(int i=0;i<4;++i){ pvv[i] = __expf(sf[i]-nm); ps += pvv[i]; }
    ps += __shfl_xor(ps, 16);
    ps += __shfl_xor(ps, 32);
    s_run = s_run*fch + ps;
    m_run = nm;
    if(w == 0){
      #pragma unroll
      for(int i=0;i<4;++i) p_lds[r*40 + hi*4 + i] = f2b(pvv[i]);
      if(hi == 0) f_lds[r] = fch;
      float* sp = scr + ((size_t)b*16 + r)*2048 + slice0 + c*16 + hi*4;
      *(float4*)sp = (float4){sf[0], sf[1], sf[2], sf[3]};
    }
    __syncthreads();                       // (B) p_lds, f_lds ready

    // ---- PV: rescale + P x V (two 8B-aligned b64 reads per fragment) ----
    f32x4 fv = *(const f32x4*)&f_lds[hi*4];
    bf16x8 pa = *(const bf16x8*)&p_lds[r*40 + hi*8];
    #pragma unroll
    for(int dc=0; dc<16; ++dc){
      acc[dc] *= fv;
      int d = w*256 + dc*16 + r;
      int col0 = (((hi & 1) ^ ((r >> 3) & 1)) << 3);
      bf16x4 blo = *(const bf16x4*)&lt[d*20 + col0];
      bf16x4 bhi = *(const bf16x4*)&lt[d*20 + col0 + 4];
      bf16x8 bv;
      bv[0]=blo[0]; bv[1]=blo[1]; bv[2]=blo[2]; bv[3]=blo[3];
      bv[4]=bhi[0]; bv[5]=bhi[1]; bv[6]=bhi[2]; bv[7]=bhi[3];
      acc[dc] = mfma16(pa, bv, acc[dc]);
    }
    __syncthreads();                       // (C) PV reads done before next deposit
  }
  // epilogue: bf16 partial ctx staged via LDS for one coalesced 32 KB store
  unsigned short* pl = lt;                 // reuse: [h 16][d 1024]
  #pragma unroll
  for(int dc=0; dc<16; ++dc)
    #pragma unroll
    for(int i=0;i<4;++i)
      pl[(hi*4+i)*1024 + w*256 + dc*16 + r] = f2b(acc[dc][i]);
  __syncthreads();
  {
    const uint4* s4 = (const uint4*)pl;
    uint4* d4 = (uint4*)(partb + (((size_t)b*64 + ns)*16)*1024);
    #pragma unroll
    for(int j=0;j<8;++j) d4[t + j*256] = s4[t + j*256];
  }
  if(w==0 && hi==0){
    msum[(((size_t)b*64 + ns)*16 + r)*2 + 0] = m_run;
    msum[(((size_t)b*64 + ns)*16 + r)*2 + 1] = s_run;
  }
}

// ---------------------------------------------------------------------------
// fin: combine 64 slices + emit probs + V-proj + fused wo-partial. grid 256.
__global__ __launch_bounds__(256) void g_fin(const unsigned short* __restrict__ partb,
    const float* __restrict__ msum, const float* __restrict__ scr,
    const float* __restrict__ wv, const float* __restrict__ wo,
    float* __restrict__ attn_out, float* __restrict__ gpart){
  int u = blockIdx.x, b = u >> 4, h = u & 15;
  int t = threadIdx.x;
  __shared__ float marr[64], earr[64], ctxs[1024], red2[256], obh[64];
  if(t < 64){
    marr[t] = msum[(((size_t)b*64 + t)*16 + h)*2 + 0];
    earr[t] = msum[(((size_t)b*64 + t)*16 + h)*2 + 1];   // temp: slice sums
  }
  __syncthreads();
  float M = -1e30f;
  for(int i=0;i<64;++i) M = fmaxf(M, marr[i]);
  float SUM = 0.f;
  for(int i=0;i<64;++i) SUM += __expf(marr[i]-M)*earr[i];
  float inv = 1.f/SUM;
  __syncthreads();
  if(t < 64) earr[t] = __expf(marr[t]-M)*inv;            // normalized weights
  __syncthreads();
  {
    const unsigned short* pb0 = partb + ((size_t)b*64*16 + h)*1024 + t*4;
    float ax=0.f, ay=0.f, az=0.f, aw=0.f;
    for(int nsq=0; nsq<64; ++nsq){
      ushort4 uu = *(const ushort4*)(pb0 + (size_t)nsq*16384);
      float e = earr[nsq];
      ax += e*b2f(uu.x); ay += e*b2f(uu.y); az += e*b2f(uu.z); aw += e*b2f(uu.w);
    }
    *(float4*)&ctxs[t*4] = (float4){ax,ay,az,aw};
  }
  const float* sp = scr + ((size_t)b*16 + h)*2048;
  float* po = attn_out + ((size_t)b*16 + h)*2048;
  #pragma unroll
  for(int i=0;i<8;++i){ int l = t + i*256; po[l] = __expf(sp[l]-M)*inv; }
  __syncthreads();
  // head V-proj: obh[v] = sum_d ctx[d]*wv[h,d,v]
  int v = t & 63, q = t >> 6;
  const float* wp = wv + ((size_t)h*1024 + q*256)*64 + v;
  float a0=0.f,a1=0.f,a2=0.f,a3=0.f;
  for(int dd=0; dd<256; dd+=4){
    a0 += ctxs[q*256+dd]   * wp[(size_t)dd*64];
    a1 += ctxs[q*256+dd+1] * wp[(size_t)(dd+1)*64];
    a2 += ctxs[q*256+dd+2] * wp[(size_t)(dd+2)*64];
    a3 += ctxs[q*256+dd+3] * wp[(size_t)(dd+3)*64];
  }
  red2[t] = a0+a1+a2+a3;
  __syncthreads();
  if(t < 64) obh[t] = red2[t]+red2[t+64]+red2[t+128]+red2[t+192];
  __syncthreads();
  // fused wo-partial: gpart[(h*16+b)*1024 + n] = sum_v obh[v]*wo[h*64+v][n]
  float accn[4] = {0.f,0.f,0.f,0.f};
  const float* wrow = wo + (size_t)h*64*1024;
  for(int vv=0; vv<64; ++vv){
    float s = obh[vv];
    const float* wr = wrow + (size_t)vv*1024;
    #pragma unroll
    for(int i=0;i<4;++i) accn[i] += s * wr[t + i*256];
  }
  #pragma unroll
  for(int i=0;i<4;++i) gpart[((size_t)h*16 + b)*1024 + t + i*256] = accn[i];
}

// ---------------------------------------------------------------------------
// LN( sum_ks parts + bias + resid ) * g + bb -> xout [+ bf16]. grid 16.
__global__ __launch_bounds__(256) void g_ln(const float* __restrict__ parts, int KS,
    const float* __restrict__ bias, const float* __restrict__ resid,
    const float* __restrict__ g, const float* __restrict__ bb,
    float* __restrict__ xout, unsigned short* __restrict__ xb16){
  int b = blockIdx.x, t = threadIdx.x;
  __shared__ float red[256];
  const float4* bias4  = (const float4*)bias;
  const float4* resid4 = (const float4*)resid + (size_t)b*256;
  const float4* parts4 = (const float4*)parts;
  float4 s = bias4[t];
  { float4 rr = resid4[t]; s.x+=rr.x; s.y+=rr.y; s.z+=rr.z; s.w+=rr.w; }
  #pragma unroll 4
  for(int k=0;k<KS;++k){
    float4 pp = parts4[((size_t)k*16 + b)*256 + t];
    s.x+=pp.x; s.y+=pp.y; s.z+=pp.z; s.w+=pp.w;
  }
  red[t] = s.x+s.y+s.z+s.w; __syncthreads();
  for(int off=128; off>0; off>>=1){ if(t<off) red[t]+=red[t+off]; __syncthreads(); }
  float mean = red[0]*(1.f/1024.f); __syncthreads();
  float dx=s.x-mean, dy=s.y-mean, dz=s.z-mean, dw=s.w-mean;
  red[t] = dx*dx+dy*dy+dz*dz+dw*dw; __syncthreads();
  for(int off=128; off>0; off>>=1){ if(t<off) red[t]+=red[t+off]; __syncthreads(); }
  float rstd = rsqrtf(red[0]*(1.f/1024.f) + 1e-5f);
  float4 g4 = ((const float4*)g)[t], b4 = ((const float4*)bb)[t];
  float4 y;
  y.x = dx*rstd*g4.x + b4.x;
  y.y = dy*rstd*g4.y + b4.y;
  y.z = dz*rstd*g4.z + b4.z;
  y.w = dw*rstd*g4.w + b4.w;
  if(xout) ((float4*)xout)[(size_t)b*256 + t] = y;
  if(xb16){
    ushort4 uu;
    uu.x = f2b(y.x); uu.y = f2b(y.y); uu.z = f2b(y.z); uu.w = f2b(y.w);
    ((ushort4*)xb16)[(size_t)b*256 + t] = uu;
  }
}

// ---------------------------------------------------------------------------
// skinny GEMM: part[ks,b,n] = A[16,Kslice] @ W[Kslice,N]   (A bf16, W fp32->bf16)
__global__ __launch_bounds__(256) void g_skg(const float* __restrict__ W,
    const unsigned short* __restrict__ A, float* __restrict__ part,
    int N, int K, int KS){
  int nt = blockIdx.x, ks = blockIdx.y;
  int Ksl = K / KS, k0b = ks * Ksl, n0 = nt*64;
  int nc = Ksl >> 5;
  __shared__ unsigned short lt[2][64*40];
  int t = threadIdx.x, lane = t & 63, w = t >> 6;
  int k_loc = t >> 3, n_off = (t & 7)*8;
  const unsigned short* apb = A + (size_t)(lane & 15)*K + (lane >> 4)*8 + k0b;
  f32x4 acc = {0.f,0.f,0.f,0.f};
  float4 x0, x1;
  auto LD = [&](int c){
    const float* wp = W + (size_t)(k0b + c*32 + k_loc)*N + n0 + n_off;
    x0 = *(const float4*)wp;
    x1 = *(const float4*)(wp + 4);
  };
  auto ST = [&](int buf){
    unsigned short* p = &lt[buf][0];
    p[(n_off+0)*40 + k_loc] = f2b(x0.x);
    p[(n_off+1)*40 + k_loc] = f2b(x0.y);
    p[(n_off+2)*40 + k_loc] = f2b(x0.z);
    p[(n_off+3)*40 + k_loc] = f2b(x0.w);
    p[(n_off+4)*40 + k_loc] = f2b(x1.x);
    p[(n_off+5)*40 + k_loc] = f2b(x1.y);
    p[(n_off+6)*40 + k_loc] = f2b(x1.z);
    p[(n_off+7)*40 + k_loc] = f2b(x1.w);
  };
  LD(0); ST(0);
  for(int c=0; c<nc; ++c){
    if(c+1 < nc) LD(c+1);
    __syncthreads();
    bf16x8 af = *(const bf16x8*)(apb + c*32);
    bf16x8 bv = *(const bf16x8*)&lt[c&1][(w*16 + (lane & 15))*40 + (lane >> 4)*8];
    acc = mfma16(af, bv, acc);
    if(c+1 < nc) ST((c+1)&1);
  }
  int col = n0 + w*16 + (lane & 15);
  int r0 = (lane >> 4)*4;
  #pragma unroll
  for(int i=0;i<4;++i)
    part[ ((size_t)ks*16 + r0 + i)*(size_t)N + col ] = acc[i];
}

// relu( sum_ks fparts + b1 ) -> h1 bf16 [16][4096]. grid 64.
__global__ __launch_bounds__(256) void g_relu(const float* __restrict__ parts, int KS,
    const float* __restrict__ b1, unsigned short* __restrict__ h1){
  int i = blockIdx.x*256 + threadIdx.x;    // float4 units over 16*1024
  int b = i >> 10, f4 = i & 1023;
  float4 s = ((const float4*)b1)[f4];
  #pragma unroll 4
  for(int k=0;k<KS;++k){
    float4 pp = ((const float4*)parts)[((size_t)k*16 + b)*1024 + f4];
    s.x+=pp.x; s.y+=pp.y; s.z+=pp.z; s.w+=pp.w;
  }
  ushort4 uu;
  uu.x = f2b(fmaxf(s.x,0.f)); uu.y = f2b(fmaxf(s.y,0.f));
  uu.z = f2b(fmaxf(s.z,0.f)); uu.w = f2b(fmaxf(s.w,0.f));
  ((ushort4*)h1)[i] = uu;
}

// ---------------------------------------------------------------------------
extern "C" void kernel_launch(void* const* d_in, const int* in_sizes, int n_in,
                              void* d_out, int out_size, void* d_ws, size_t ws_size,
                              hipStream_t stream){
  const float* dec    = (const float*)d_in[0];
  const float* hist   = (const float*)d_in[1];
  const float* enc    = (const float*)d_in[2];
  const float* wq_s   = (const float*)d_in[3];
  const float* wk_s   = (const float*)d_in[4];
  const float* wv_s   = (const float*)d_in[5];
  const float* wo_s   = (const float*)d_in[6];
  const float* bo_s   = (const float*)d_in[7];
  const float* ln1_g  = (const float*)d_in[8];
  const float* ln1_b  = (const float*)d_in[9];
  const float* wq_c   = (const float*)d_in[10];
  const float* wk_c   = (const float*)d_in[11];
  const float* wv_c   = (const float*)d_in[12];
  const float* wo_c   = (const float*)d_in[13];
  const float* bo_c   = (const float*)d_in[14];
  const float* ln2_g  = (const float*)d_in[15];
  const float* ln2_b  = (const float*)d_in[16];
  const float* w1     = (const float*)d_in[17];
  const float* b1     = (const float*)d_in[18];
  const float* w2     = (const float*)d_in[19];
  const float* b2     = (const float*)d_in[20];
  const float* ln3_g  = (const float*)d_in[21];
  const float* ln3_b  = (const float*)d_in[22];

  float* out  = (float*)d_out;             // [16][1024]
  float* slf  = out + 16384;               // [16][16][2048]
  float* enco = out + 16384 + 524288;      // [16][16][2048]

  char* w = (char*)d_ws;
  float*          scr    = (float*)(w + 0x0000000);           // 2 MB  [16][16][2048]
  unsigned short* partb  = (unsigned short*)(w + 0x0200000);  // 32 MB [16][64][16][1024] bf16
  float*          msum   = (float*)(w + 0x2200000);           // 128K  [16][64][16][2]
  unsigned short* qpb    = (unsigned short*)(w + 0x2240000);  // 512K  [16][16][1024]
  float*          x1     = (float*)(w + 0x22C0000);           // 64K
  float*          x2     = (float*)(w + 0x22D0000);           // 64K
  unsigned short* x2b    = (unsigned short*)(w + 0x22E0000);  // 32K
  unsigned short* h1b    = (unsigned short*)(w + 0x22F0000);  // 128K  [16][4096]
  float*          gpart  = (float*)(w + 0x2400000);           // 1 MB  [16][16][1024]
  float*          fpart  = (float*)(w + 0x2500000);           // 2 MB  [8][16][4096]
  float*          g2part = (float*)(w + 0x2700000);           // 2 MB  [32][16][1024]

  // ---- self attention ----
  g_qp2 <<<256,  256, 0, stream>>>(dec, wq_s, wk_s, qpb);
  g_attn<<<1024, 256, 0, stream>>>(hist, dec, qpb, scr, partb, msum, 2047);
  g_fin <<<256,  256, 0, stream>>>(partb, msum, scr, wv_s, wo_s, slf, gpart);
  g_ln  <<<16,   256, 0, stream>>>(gpart, 16, bo_s, dec, ln1_g, ln1_b, x1, (unsigned short*)0);

  // ---- cross attention ----
  g_qp2 <<<256,  256, 0, stream>>>(x1, wq_c, wk_c, qpb);
  g_attn<<<1024, 256, 0, stream>>>(enc, dec, qpb, scr, partb, msum, 2048);
  g_fin <<<256,  256, 0, stream>>>(partb, msum, scr, wv_c, wo_c, enco, gpart);
  g_ln  <<<16,   256, 0, stream>>>(gpart, 16, bo_c, x1, ln2_g, ln2_b, x2, x2b);

  // ---- FFN + final LN ----
  g_skg <<<dim3(64,8),  256, 0, stream>>>(w1, x2b, fpart, 4096, 1024, 8);
  g_relu<<<64,  256, 0, stream>>>(fpart, 8, b1, h1b);
  g_skg <<<dim3(16,32), 256, 0, stream>>>(w2, h1b, g2part, 1024, 4096, 32);
  g_ln  <<<16,  256, 0, stream>>>(g2part, 32, b2, x2, ln3_g, ln3_b, out, (unsigned short*)0);
}